// Round 1
// baseline (350.982 us; speedup 1.0000x reference)
//
#include <hip/hip_runtime.h>

#define NEG_SLOPE 0.2f

// -------- edge helpers: edge_index is [2,E] int32 row-major; self-loops appended --------
__device__ __forceinline__ void edge_sd(const int* ei, int E, int e, int& s, int& d) {
    if (e < E) { s = ei[e]; d = ei[E + e]; }
    else       { int v = e - E; s = v; d = v; }
}

__global__ void zero_kernel(int* p, int n) {
    int i = blockIdx.x * blockDim.x + threadIdx.x;
    if (i < n) p[i] = 0;
}

__global__ void deg_kernel(const int* ei, int E, int N, int* deg) {
    int e = blockIdx.x * blockDim.x + threadIdx.x;
    if (e >= E + N) return;
    int s, d; edge_sd(ei, E, e, s, d);
    atomicAdd(&deg[d], 1);
}

// single-block exclusive scan of deg[0..n) -> offsets[0..n], offsets[n] = total
__global__ void scan_kernel(const int* deg, int* offsets, int n) {
    __shared__ int part[1024];
    int t = threadIdx.x;
    int chunk = (n + 1023) / 1024;
    int beg = t * chunk;
    int s = 0;
    for (int i = 0; i < chunk; ++i) {
        int idx = beg + i;
        if (idx < n) s += deg[idx];
    }
    part[t] = s;
    __syncthreads();
    // Hillis-Steele inclusive scan
    for (int off = 1; off < 1024; off <<= 1) {
        int v = (t >= off) ? part[t - off] : 0;
        __syncthreads();
        part[t] += v;
        __syncthreads();
    }
    if (t == 1023) offsets[n] = part[1023];
    int run = (t == 0) ? 0 : part[t - 1];
    for (int i = 0; i < chunk; ++i) {
        int idx = beg + i;
        if (idx < n) { offsets[idx] = run; run += deg[idx]; }
    }
}

__global__ void fill_kernel(const int* ei, int E, int N, const int* offsets,
                            int* cursor, int* csr_src) {
    int e = blockIdx.x * blockDim.x + threadIdx.x;
    if (e >= E + N) return;
    int s, d; edge_sd(ei, E, e, s, d);
    int pos = offsets[d] + atomicAdd(&cursor[d], 1);
    csr_src[pos] = s;
}

// xl1[n, j] = sum_k x[n,k]*W1[k,j]   (IN_DIM=6, JOUT=512)
__global__ void xw1_kernel(const float* __restrict__ x, const float* __restrict__ W,
                           float* __restrict__ xl, int n) {
    int idx = blockIdx.x * blockDim.x + threadIdx.x;
    if (idx >= n * 512) return;
    int node = idx >> 9;
    int j = idx & 511;
    const float* xr = x + node * 6;
    float s = 0.f;
#pragma unroll
    for (int k = 0; k < 6; ++k) s += xr[k] * W[k * 512 + j];
    xl[idx] = s;
}

// es/ed[n,h] = sum_c xl[n,h,c]*a_{src,dst}[h,c]   — one wave per (node, head)
template <int H>
__global__ void attn_scores(const float* __restrict__ xl, const float* __restrict__ a_src,
                            const float* __restrict__ a_dst,
                            float* __restrict__ es, float* __restrict__ ed, int n) {
    int node = blockIdx.x;
    int h = threadIdx.x >> 6, lane = threadIdx.x & 63;
    const float* row = xl + ((size_t)node * H + h) * 128;
    float r0 = row[lane], r1 = row[lane + 64];
    float ss = r0 * a_src[h * 128 + lane] + r1 * a_src[h * 128 + lane + 64];
    float sd = r0 * a_dst[h * 128 + lane] + r1 * a_dst[h * 128 + lane + 64];
#pragma unroll
    for (int off = 32; off; off >>= 1) {
        ss += __shfl_down(ss, off);
        sd += __shfl_down(sd, off);
    }
    if (lane == 0) { es[node * H + h] = ss; ed[node * H + h] = sd; }
}

// Aggregation: one wave per (node, head). Two-pass softmax over CSR incoming edges,
// lane covers channels c=lane and c=lane+64. out[n, h*128+c] = relu(acc/denom + bias).
template <int H>
__global__ void gat_agg(const float* __restrict__ xl, const float* __restrict__ es,
                        const float* __restrict__ ed, const int* __restrict__ offsets,
                        const int* __restrict__ csr_src, const float* __restrict__ bias,
                        float* __restrict__ out, int n) {
    int node = blockIdx.x;
    int h = threadIdx.x >> 6, lane = threadIdx.x & 63;
    int beg = offsets[node], end = offsets[node + 1];
    float edv = ed[node * H + h];
    // pass 1: running max of leaky_relu(es[s]+ed[d])
    float m = -1e30f;
    for (int i = beg; i < end; ++i) {
        int s = csr_src[i];
        float w = es[s * H + h] + edv;
        w = (w > 0.f) ? w : NEG_SLOPE * w;
        m = fmaxf(m, w);
    }
    // pass 2: exp-weighted feature sum
    float denom = 0.f, acc0 = 0.f, acc1 = 0.f;
    int c0 = lane, c1 = lane + 64;
    for (int i = beg; i < end; ++i) {
        int s = csr_src[i];
        float w = es[s * H + h] + edv;
        w = (w > 0.f) ? w : NEG_SLOPE * w;
        float ex = __expf(w - m);
        denom += ex;
        const float* row = xl + ((size_t)s * H + h) * 128;
        acc0 += ex * row[c0];
        acc1 += ex * row[c1];
    }
    float inv = 1.f / denom;
    int j0 = h * 128 + c0, j1 = h * 128 + c1;
    float o0 = acc0 * inv + bias[j0];
    float o1 = acc1 * inv + bias[j1];
    size_t base = (size_t)node * (H * 128);
    out[base + j0] = fmaxf(o0, 0.f);
    out[base + j1] = fmaxf(o1, 0.f);
}

// xl2 = h @ W2 : [N,512]@[512,128]. 8 nodes per block, 128 threads (one column each).
__global__ void xw2_kernel(const float* __restrict__ h, const float* __restrict__ W2,
                           float* __restrict__ xl2, int n) {
    __shared__ float hs[8][512];
    int j = threadIdx.x;
    int n0 = blockIdx.x * 8;
    for (int i = threadIdx.x; i < 8 * 512; i += 128) {
        int r = i >> 9, c = i & 511;
        int node = n0 + r;
        hs[r][c] = (node < n) ? h[(size_t)node * 512 + c] : 0.f;
    }
    __syncthreads();
    float acc[8] = {0.f, 0.f, 0.f, 0.f, 0.f, 0.f, 0.f, 0.f};
    for (int k = 0; k < 512; ++k) {
        float w = W2[k * 128 + j];
#pragma unroll
        for (int r = 0; r < 8; ++r) acc[r] += hs[r][k] * w;
    }
    for (int r = 0; r < 8; ++r) {
        int node = n0 + r;
        if (node < n) xl2[(size_t)node * 128 + j] = acc[r];
    }
}

// pool: gsum[batch[n], c] += h2[n, c]; gcnt[batch[n]] += 1 (once per node)
__global__ void pool_kernel(const float* __restrict__ h2, const int* __restrict__ batch,
                            float* __restrict__ gsum, float* __restrict__ gcnt, int n) {
    int idx = blockIdx.x * blockDim.x + threadIdx.x;
    if (idx >= n * 128) return;
    int node = idx >> 7, c = idx & 127;
    int b = batch[node];
    atomicAdd(&gsum[b * 128 + c], h2[idx]);
    if (c == 0) atomicAdd(&gcnt[b], 1.0f);
}

// MLP head: one block (128 threads) per graph
__global__ void mlp_kernel(const float* __restrict__ gsum, const float* __restrict__ gcnt,
                           const float* __restrict__ mw1, const float* __restrict__ mb1,
                           const float* __restrict__ mw2, const float* __restrict__ mb2,
                           float* __restrict__ out) {
    __shared__ float gm[128], t[128];
    int g = blockIdx.x, j = threadIdx.x;
    float cnt = fmaxf(gcnt[g], 1.f);
    gm[j] = gsum[g * 128 + j] / cnt;
    __syncthreads();
    float s = mb1[j];
    for (int k = 0; k < 128; ++k) s += gm[k] * mw1[k * 128 + j];
    t[j] = fmaxf(s, 0.f);
    __syncthreads();
    if (j < 4) {
        float o = mb2[j];
        for (int k = 0; k < 128; ++k) o += t[k] * mw2[k * 4 + j];
        out[g * 4 + j] = o;
    }
}

extern "C" void kernel_launch(void* const* d_in, const int* in_sizes, int n_in,
                              void* d_out, int out_size, void* d_ws, size_t ws_size,
                              hipStream_t stream) {
    const float* x       = (const float*)d_in[0];
    const int*   ei      = (const int*)d_in[1];
    const int*   batch   = (const int*)d_in[2];
    const float* W1      = (const float*)d_in[3];
    const float* a_src1  = (const float*)d_in[4];
    const float* a_dst1  = (const float*)d_in[5];
    const float* b1      = (const float*)d_in[6];
    const float* W2      = (const float*)d_in[7];
    const float* a_src2  = (const float*)d_in[8];
    const float* a_dst2  = (const float*)d_in[9];
    const float* b2      = (const float*)d_in[10];
    const float* mw1     = (const float*)d_in[11];
    const float* mb1     = (const float*)d_in[12];
    const float* mw2     = (const float*)d_in[13];
    const float* mb2     = (const float*)d_in[14];
    float* out = (float*)d_out;

    const int N = in_sizes[0] / 6;      // 10000
    const int E = in_sizes[1] / 2;      // 160000
    const int ET = E + N;               // with self-loops
    const int G = 64;

    // ---- workspace bump allocator (16B aligned) ----
    char* ws = (char*)d_ws;
    size_t off = 0;
    auto alloc = [&](size_t bytes) {
        void* p = ws + off;
        off += (bytes + 15) & ~(size_t)15;
        return p;
    };
    float* xl1     = (float*)alloc((size_t)N * 512 * 4);
    float* hbuf    = (float*)alloc((size_t)N * 512 * 4);
    float* xl2     = (float*)alloc((size_t)N * 128 * 4);
    float* h2      = (float*)alloc((size_t)N * 128 * 4);
    float* es1     = (float*)alloc((size_t)N * 4 * 4);
    float* ed1     = (float*)alloc((size_t)N * 4 * 4);
    float* es2     = (float*)alloc((size_t)N * 4);
    float* ed2     = (float*)alloc((size_t)N * 4);
    int*   offsets = (int*)alloc((size_t)(N + 1) * 4);
    // contiguous zero region: deg, cursor, gsum, gcnt
    int*   zbase   = (int*)alloc((size_t)N * 4 + (size_t)N * 4 + (size_t)G * 128 * 4 + (size_t)G * 4);
    int*   deg     = zbase;
    int*   cursor  = zbase + N;
    float* gsum    = (float*)(zbase + 2 * N);
    float* gcnt    = gsum + G * 128;
    int*   csr_src = (int*)alloc((size_t)ET * 4);
    (void)ws_size; (void)n_in; (void)out_size;

    const int zn = 2 * N + G * 128 + G;

    // 1) zero accumulators
    zero_kernel<<<(zn + 255) / 256, 256, 0, stream>>>(zbase, zn);
    // 2) CSR build
    deg_kernel<<<(ET + 255) / 256, 256, 0, stream>>>(ei, E, N, deg);
    scan_kernel<<<1, 1024, 0, stream>>>(deg, offsets, N);
    fill_kernel<<<(ET + 255) / 256, 256, 0, stream>>>(ei, E, N, offsets, cursor, csr_src);
    // 3) GAT1
    xw1_kernel<<<((N * 512) + 255) / 256, 256, 0, stream>>>(x, W1, xl1, N);
    attn_scores<4><<<N, 256, 0, stream>>>(xl1, a_src1, a_dst1, es1, ed1, N);
    gat_agg<4><<<N, 256, 0, stream>>>(xl1, es1, ed1, offsets, csr_src, b1, hbuf, N);
    // 4) GAT2
    xw2_kernel<<<(N + 7) / 8, 128, 0, stream>>>(hbuf, W2, xl2, N);
    attn_scores<1><<<N, 64, 0, stream>>>(xl2, a_src2, a_dst2, es2, ed2, N);
    gat_agg<1><<<N, 64, 0, stream>>>(xl2, es2, ed2, offsets, csr_src, b2, h2, N);
    // 5) pool + MLP
    pool_kernel<<<((N * 128) + 255) / 256, 256, 0, stream>>>(h2, batch, gsum, gcnt, N);
    mlp_kernel<<<G, 128, 0, stream>>>(gsum, gcnt, mw1, mb1, mw2, mb2, out);
}

// Round 2
// 303.164 us; speedup vs baseline: 1.1577x; 1.1577x over previous
//
#include <hip/hip_runtime.h>

#define NEG_SLOPE 0.2f

// -------- edge helpers: edge_index is [2,E] int32 row-major; self-loops appended --------
__device__ __forceinline__ void edge_sd(const int* ei, int E, int e, int& s, int& d) {
    if (e < E) { s = ei[e]; d = ei[E + e]; }
    else       { int v = e - E; s = v; d = v; }
}

__global__ void zero_kernel(int* p, int n) {
    int i = blockIdx.x * blockDim.x + threadIdx.x;
    if (i < n) p[i] = 0;
}

__global__ void deg_kernel(const int* ei, int E, int N, int* deg) {
    int e = blockIdx.x * blockDim.x + threadIdx.x;
    if (e >= E + N) return;
    int s, d; edge_sd(ei, E, e, s, d);
    atomicAdd(&deg[d], 1);
}

// single-block exclusive scan of deg[0..n) -> offsets[0..n], offsets[n] = total
__global__ void scan_kernel(const int* deg, int* offsets, int n) {
    __shared__ int part[1024];
    int t = threadIdx.x;
    int chunk = (n + 1023) / 1024;
    int beg = t * chunk;
    int s = 0;
    for (int i = 0; i < chunk; ++i) {
        int idx = beg + i;
        if (idx < n) s += deg[idx];
    }
    part[t] = s;
    __syncthreads();
    for (int off = 1; off < 1024; off <<= 1) {
        int v = (t >= off) ? part[t - off] : 0;
        __syncthreads();
        part[t] += v;
        __syncthreads();
    }
    if (t == 1023) offsets[n] = part[1023];
    int run = (t == 0) ? 0 : part[t - 1];
    for (int i = 0; i < chunk; ++i) {
        int idx = beg + i;
        if (idx < n) { offsets[idx] = run; run += deg[idx]; }
    }
}

__global__ void fill_kernel(const int* ei, int E, int N, const int* offsets,
                            int* cursor, int* csr_src) {
    int e = blockIdx.x * blockDim.x + threadIdx.x;
    if (e >= E + N) return;
    int s, d; edge_sd(ei, E, e, s, d);
    int pos = offsets[d] + atomicAdd(&cursor[d], 1);
    csr_src[pos] = s;
}

// Fused: xl1 = x@W1 (per node, 512 outputs) + es1/ed1 attention scores.
// Block = 256 threads = 4 waves; wave h == head h; thread t computes j=2t, 2t+1.
__global__ void xw1_attn(const float* __restrict__ x, const float* __restrict__ W1,
                         const float* __restrict__ a_src, const float* __restrict__ a_dst,
                         float* __restrict__ xl, float* __restrict__ es, float* __restrict__ ed,
                         int n) {
    int node = blockIdx.x;
    int t = threadIdx.x;
    __shared__ float xs[6];
    if (t < 6) xs[t] = x[node * 6 + t];
    __syncthreads();
    int j0 = 2 * t, j1 = 2 * t + 1;
    float v0 = 0.f, v1 = 0.f;
#pragma unroll
    for (int k = 0; k < 6; ++k) {
        v0 += xs[k] * W1[k * 512 + j0];
        v1 += xs[k] * W1[k * 512 + j1];
    }
    float2* xlp = (float2*)(xl + (size_t)node * 512);
    xlp[t] = make_float2(v0, v1);
    // head of channel j0 is j0>>7 == t>>6 == wave index; a_src is flat [512]
    float ps = v0 * a_src[j0] + v1 * a_src[j1];
    float pd = v0 * a_dst[j0] + v1 * a_dst[j1];
#pragma unroll
    for (int off = 32; off; off >>= 1) {
        ps += __shfl_xor(ps, off);
        pd += __shfl_xor(pd, off);
    }
    int h = t >> 6, lane = t & 63;
    if (lane == 0) { es[node * 4 + h] = ps; ed[node * 4 + h] = pd; }
}

// attention scores for GAT2 (H=1): one wave per node
__global__ void attn_scores1(const float* __restrict__ xl, const float* __restrict__ a_src,
                             const float* __restrict__ a_dst,
                             float* __restrict__ es, float* __restrict__ ed, int n) {
    int node = blockIdx.x;
    int lane = threadIdx.x & 63;
    const float* row = xl + (size_t)node * 128;
    float r0 = row[lane], r1 = row[lane + 64];
    float ss = r0 * a_src[lane] + r1 * a_src[lane + 64];
    float sd = r0 * a_dst[lane] + r1 * a_dst[lane + 64];
#pragma unroll
    for (int off = 32; off; off >>= 1) {
        ss += __shfl_xor(ss, off);
        sd += __shfl_xor(sd, off);
    }
    if (lane == 0) { es[node] = ss; ed[node] = sd; }
}

// Aggregation: one wave per (node, head).
// Phase a (lane-parallel): all <=64 edge weights at once, wave-reduce max/sum, exp.
// Phase b (serial over edges): only the float2 row gather, independent loads.
// Online rescale across 64-edge chunks handles deg>64; single-chunk path is exact two-pass.
template <int H, bool POOL>
__global__ void gat_agg(const float* __restrict__ xl, const float* __restrict__ es,
                        const float* __restrict__ ed, const int* __restrict__ offsets,
                        const int* __restrict__ csr_src, const float* __restrict__ bias,
                        float* __restrict__ out, const int* __restrict__ batch,
                        float* __restrict__ gsum, float* __restrict__ gcnt, int n) {
    int node = blockIdx.x;
    int h = (H > 1) ? (threadIdx.x >> 6) : 0;
    int lane = threadIdx.x & 63;
    int beg = offsets[node], end = offsets[node + 1];
    float edv = ed[node * H + h];
    float m = -1e30f, denom = 0.f;
    float accx = 0.f, accy = 0.f;
    for (int chunk = beg; chunk < end; chunk += 64) {
        int i = chunk + lane;
        bool valid = i < end;
        int s = valid ? csr_src[i] : 0;
        float w = -1e30f;
        if (valid) {
            w = es[s * H + h] + edv;
            w = (w > 0.f) ? w : NEG_SLOPE * w;
        }
        float cm = w;
#pragma unroll
        for (int off = 32; off; off >>= 1) cm = fmaxf(cm, __shfl_xor(cm, off));
        float newm = fmaxf(m, cm);
        float scale = __expf(m - newm);   // first chunk: exp(-huge)=0, acc/denom are 0
        accx *= scale; accy *= scale; denom *= scale;
        float ex = valid ? __expf(w - newm) : 0.f;
        float sum = ex;
#pragma unroll
        for (int off = 32; off; off >>= 1) sum += __shfl_xor(sum, off);
        denom += sum;
        m = newm;
        int cnt = end - chunk; if (cnt > 64) cnt = 64;
        for (int t = 0; t < cnt; ++t) {
            float wt = __shfl(ex, t);
            int st = __shfl(s, t);
            const float2* row = (const float2*)(xl + ((size_t)st * H + h) * 128);
            float2 rv = row[lane];
            accx += wt * rv.x;
            accy += wt * rv.y;
        }
    }
    float inv = 1.f / denom;
    int j0 = h * 128 + 2 * lane;
    float o0 = fmaxf(accx * inv + bias[j0], 0.f);
    float o1 = fmaxf(accy * inv + bias[j0 + 1], 0.f);
    if (POOL) {
        int b = batch[node];
        atomicAdd(&gsum[b * 128 + j0], o0);
        atomicAdd(&gsum[b * 128 + j0 + 1], o1);
        if (lane == 0) atomicAdd(&gcnt[b], 1.f);
    } else {
        float2* op = (float2*)(out + (size_t)node * (H * 128));
        op[h * 64 + lane] = make_float2(o0, o1);
    }
}

// xl2 = h @ W2 : [N,512]@[512,128]. 16 nodes per block (625 blocks exactly), 256 threads.
// Thread t: col j = t&127, node group rg = t>>7 (8 nodes). float4 LDS broadcast reads.
__global__ void xw2_kernel(const float* __restrict__ h, const float* __restrict__ W2,
                           float* __restrict__ xl2, int n) {
    __shared__ float hs[16][512];
    int t = threadIdx.x;
    int n0 = blockIdx.x * 16;
    const float4* hsrc = (const float4*)(h + (size_t)n0 * 512);
    float4* hdst = (float4*)&hs[0][0];
#pragma unroll
    for (int i = 0; i < 8; ++i) hdst[t + 256 * i] = hsrc[t + 256 * i];
    __syncthreads();
    int j = t & 127, rg = t >> 7;
    float acc[8] = {0.f, 0.f, 0.f, 0.f, 0.f, 0.f, 0.f, 0.f};
    for (int k = 0; k < 512; k += 4) {
        float wx = W2[(k + 0) * 128 + j];
        float wy = W2[(k + 1) * 128 + j];
        float wz = W2[(k + 2) * 128 + j];
        float ww = W2[(k + 3) * 128 + j];
#pragma unroll
        for (int r = 0; r < 8; ++r) {
            float4 hv = *(const float4*)&hs[rg * 8 + r][k];
            acc[r] += hv.x * wx + hv.y * wy + hv.z * wz + hv.w * ww;
        }
    }
#pragma unroll
    for (int r = 0; r < 8; ++r)
        xl2[(size_t)(n0 + rg * 8 + r) * 128 + j] = acc[r];
}

// MLP head: one block (128 threads) per graph
__global__ void mlp_kernel(const float* __restrict__ gsum, const float* __restrict__ gcnt,
                           const float* __restrict__ mw1, const float* __restrict__ mb1,
                           const float* __restrict__ mw2, const float* __restrict__ mb2,
                           float* __restrict__ out) {
    __shared__ float gm[128], tbuf[128];
    int g = blockIdx.x, j = threadIdx.x;
    float cnt = fmaxf(gcnt[g], 1.f);
    gm[j] = gsum[g * 128 + j] / cnt;
    __syncthreads();
    float s = mb1[j];
    for (int k = 0; k < 128; ++k) s += gm[k] * mw1[k * 128 + j];
    tbuf[j] = fmaxf(s, 0.f);
    __syncthreads();
    if (j < 4) {
        float o = mb2[j];
        for (int k = 0; k < 128; ++k) o += tbuf[k] * mw2[k * 4 + j];
        out[g * 4 + j] = o;
    }
}

extern "C" void kernel_launch(void* const* d_in, const int* in_sizes, int n_in,
                              void* d_out, int out_size, void* d_ws, size_t ws_size,
                              hipStream_t stream) {
    const float* x       = (const float*)d_in[0];
    const int*   ei      = (const int*)d_in[1];
    const int*   batch   = (const int*)d_in[2];
    const float* W1      = (const float*)d_in[3];
    const float* a_src1  = (const float*)d_in[4];
    const float* a_dst1  = (const float*)d_in[5];
    const float* b1      = (const float*)d_in[6];
    const float* W2      = (const float*)d_in[7];
    const float* a_src2  = (const float*)d_in[8];
    const float* a_dst2  = (const float*)d_in[9];
    const float* b2      = (const float*)d_in[10];
    const float* mw1     = (const float*)d_in[11];
    const float* mb1     = (const float*)d_in[12];
    const float* mw2     = (const float*)d_in[13];
    const float* mb2     = (const float*)d_in[14];
    float* out = (float*)d_out;

    const int N = in_sizes[0] / 6;      // 10000
    const int E = in_sizes[1] / 2;      // 160000
    const int ET = E + N;               // with self-loops
    const int G = 64;

    char* ws = (char*)d_ws;
    size_t off = 0;
    auto alloc = [&](size_t bytes) {
        void* p = ws + off;
        off += (bytes + 15) & ~(size_t)15;
        return p;
    };
    float* xl1     = (float*)alloc((size_t)N * 512 * 4);
    float* hbuf    = (float*)alloc((size_t)N * 512 * 4);
    float* xl2     = (float*)alloc((size_t)N * 128 * 4);
    float* es1     = (float*)alloc((size_t)N * 4 * 4);
    float* ed1     = (float*)alloc((size_t)N * 4 * 4);
    float* es2     = (float*)alloc((size_t)N * 4);
    float* ed2     = (float*)alloc((size_t)N * 4);
    int*   offsets = (int*)alloc((size_t)(N + 1) * 4);
    int*   zbase   = (int*)alloc((size_t)N * 4 + (size_t)N * 4 + (size_t)G * 128 * 4 + (size_t)G * 4);
    int*   deg     = zbase;
    int*   cursor  = zbase + N;
    float* gsum    = (float*)(zbase + 2 * N);
    float* gcnt    = gsum + G * 128;
    int*   csr_src = (int*)alloc((size_t)ET * 4);
    (void)ws_size; (void)n_in; (void)out_size;

    const int zn = 2 * N + G * 128 + G;

    zero_kernel<<<(zn + 255) / 256, 256, 0, stream>>>(zbase, zn);
    deg_kernel<<<(ET + 255) / 256, 256, 0, stream>>>(ei, E, N, deg);
    scan_kernel<<<1, 1024, 0, stream>>>(deg, offsets, N);
    fill_kernel<<<(ET + 255) / 256, 256, 0, stream>>>(ei, E, N, offsets, cursor, csr_src);

    xw1_attn<<<N, 256, 0, stream>>>(x, W1, a_src1, a_dst1, xl1, es1, ed1, N);
    gat_agg<4, false><<<N, 256, 0, stream>>>(xl1, es1, ed1, offsets, csr_src, b1,
                                             hbuf, nullptr, nullptr, nullptr, N);
    xw2_kernel<<<N / 16, 256, 0, stream>>>(hbuf, W2, xl2, N);
    attn_scores1<<<N, 64, 0, stream>>>(xl2, a_src2, a_dst2, es2, ed2, N);
    gat_agg<1, true><<<N, 64, 0, stream>>>(xl2, es2, ed2, offsets, csr_src, b2,
                                           nullptr, batch, gsum, gcnt, N);
    mlp_kernel<<<G, 128, 0, stream>>>(gsum, gcnt, mw1, mb1, mw2, mb2, out);
}

// Round 4
// 289.630 us; speedup vs baseline: 1.2118x; 1.0467x over previous
//
#include <hip/hip_runtime.h>

#define NEG_SLOPE 0.2f

// -------- edge helpers: edge_index is [2,E] int32 row-major; self-loops appended --------
__device__ __forceinline__ void edge_sd(const int* ei, int E, int e, int& s, int& d) {
    if (e < E) { s = ei[e]; d = ei[E + e]; }
    else       { int v = e - E; s = v; d = v; }
}

__global__ void zero_kernel(int* p, int n) {
    int i = blockIdx.x * blockDim.x + threadIdx.x;
    if (i < n) p[i] = 0;
}

__global__ void deg_kernel(const int* ei, int E, int N, int* deg) {
    int e = blockIdx.x * blockDim.x + threadIdx.x;
    if (e >= E + N) return;
    int s, d; edge_sd(ei, E, e, s, d);
    atomicAdd(&deg[d], 1);
}

// single-block exclusive scan of deg[0..n) -> offsets[0..n], offsets[n] = total
__global__ void scan_kernel(const int* deg, int* offsets, int n) {
    __shared__ int part[1024];
    int t = threadIdx.x;
    int chunk = (n + 1023) / 1024;
    int beg = t * chunk;
    int s = 0;
    for (int i = 0; i < chunk; ++i) {
        int idx = beg + i;
        if (idx < n) s += deg[idx];
    }
    part[t] = s;
    __syncthreads();
    for (int off = 1; off < 1024; off <<= 1) {
        int v = (t >= off) ? part[t - off] : 0;
        __syncthreads();
        part[t] += v;
        __syncthreads();
    }
    if (t == 1023) offsets[n] = part[1023];
    int run = (t == 0) ? 0 : part[t - 1];
    for (int i = 0; i < chunk; ++i) {
        int idx = beg + i;
        if (idx < n) { offsets[idx] = run; run += deg[idx]; }
    }
}

__global__ void fill_kernel(const int* ei, int E, int N, const int* offsets,
                            int* cursor, int* csr_src) {
    int e = blockIdx.x * blockDim.x + threadIdx.x;
    if (e >= E + N) return;
    int s, d; edge_sd(ei, E, e, s, d);
    int pos = offsets[d] + atomicAdd(&cursor[d], 1);
    csr_src[pos] = s;
}

// Fused: xl1 = x@W1 (per node, 512 outputs) + es1/ed1 attention scores.
// Block = 256 threads = 4 waves; wave h == head h; thread t computes j=2t, 2t+1.
__global__ void xw1_attn(const float* __restrict__ x, const float* __restrict__ W1,
                         const float* __restrict__ a_src, const float* __restrict__ a_dst,
                         float* __restrict__ xl, float* __restrict__ es, float* __restrict__ ed,
                         int n) {
    int node = blockIdx.x;
    int t = threadIdx.x;
    __shared__ float xs[6];
    if (t < 6) xs[t] = x[node * 6 + t];
    __syncthreads();
    int j0 = 2 * t, j1 = 2 * t + 1;
    float v0 = 0.f, v1 = 0.f;
#pragma unroll
    for (int k = 0; k < 6; ++k) {
        v0 += xs[k] * W1[k * 512 + j0];
        v1 += xs[k] * W1[k * 512 + j1];
    }
    float2* xlp = (float2*)(xl + (size_t)node * 512);
    xlp[t] = make_float2(v0, v1);
    float ps = v0 * a_src[j0] + v1 * a_src[j1];
    float pd = v0 * a_dst[j0] + v1 * a_dst[j1];
#pragma unroll
    for (int off = 32; off; off >>= 1) {
        ps += __shfl_xor(ps, off);
        pd += __shfl_xor(pd, off);
    }
    int h = t >> 6, lane = t & 63;
    if (lane == 0) { es[node * 4 + h] = ps; ed[node * 4 + h] = pd; }
}

// Aggregation. H=4: one node per block (256 thr), wave = head.
//              H=1: four nodes per block (256 thr), wave = node.
// Phase a (lane-parallel): <=64 edge weights at once, wave-reduce max/sum, exp.
// Phase b: feature gather, 4x unrolled with independent accumulators (4 loads in flight).
template <int H, bool POOL>
__global__ void gat_agg(const float* __restrict__ xl, const float* __restrict__ es,
                        const float* __restrict__ ed, const int* __restrict__ offsets,
                        const int* __restrict__ csr_src, const float* __restrict__ bias,
                        float* __restrict__ out, const int* __restrict__ batch,
                        float* __restrict__ gsum, float* __restrict__ gcnt, int n) {
    int wave = threadIdx.x >> 6;
    int lane = threadIdx.x & 63;
    int node, h;
    if (H == 4) { node = blockIdx.x; h = wave; }
    else        { node = blockIdx.x * 4 + wave; h = 0; }
    int beg = offsets[node], end = offsets[node + 1];
    float edv = ed[node * H + h];
    const float2* xl2p = (const float2*)xl;
    float m = -1e30f, denom = 0.f;
    float accx = 0.f, accy = 0.f;
    for (int chunk = beg; chunk < end; chunk += 64) {
        int i = chunk + lane;
        bool valid = i < end;
        int s = valid ? csr_src[i] : 0;
        float w = -1e30f;
        if (valid) {
            w = es[s * H + h] + edv;
            w = (w > 0.f) ? w : NEG_SLOPE * w;
        }
        float cm = w;
#pragma unroll
        for (int off = 32; off; off >>= 1) cm = fmaxf(cm, __shfl_xor(cm, off));
        float newm = fmaxf(m, cm);
        float scale = __expf(m - newm);   // first chunk: exp(-huge)=0, acc/denom are 0
        accx *= scale; accy *= scale; denom *= scale;
        float ex = valid ? __expf(w - newm) : 0.f;
        float sum = ex;
#pragma unroll
        for (int off = 32; off; off >>= 1) sum += __shfl_xor(sum, off);
        denom += sum;
        m = newm;
        int cnt = end - chunk; if (cnt > 64) cnt = 64;
        // 4x unrolled gather: independent accumulators keep 4 loads in flight
        float ax0 = 0.f, ay0 = 0.f, ax1 = 0.f, ay1 = 0.f;
        float ax2 = 0.f, ay2 = 0.f, ax3 = 0.f, ay3 = 0.f;
        int tt = 0;
        for (; tt + 4 <= cnt; tt += 4) {
            float w0 = __shfl(ex, tt), w1 = __shfl(ex, tt + 1);
            float w2 = __shfl(ex, tt + 2), w3 = __shfl(ex, tt + 3);
            int s0 = __shfl(s, tt), s1 = __shfl(s, tt + 1);
            int s2 = __shfl(s, tt + 2), s3 = __shfl(s, tt + 3);
            float2 v0 = xl2p[((size_t)s0 * H + h) * 64 + lane];
            float2 v1 = xl2p[((size_t)s1 * H + h) * 64 + lane];
            float2 v2 = xl2p[((size_t)s2 * H + h) * 64 + lane];
            float2 v3 = xl2p[((size_t)s3 * H + h) * 64 + lane];
            ax0 += w0 * v0.x; ay0 += w0 * v0.y;
            ax1 += w1 * v1.x; ay1 += w1 * v1.y;
            ax2 += w2 * v2.x; ay2 += w2 * v2.y;
            ax3 += w3 * v3.x; ay3 += w3 * v3.y;
        }
        for (; tt < cnt; ++tt) {
            float wt = __shfl(ex, tt);
            int st = __shfl(s, tt);
            float2 rv = xl2p[((size_t)st * H + h) * 64 + lane];
            ax0 += wt * rv.x; ay0 += wt * rv.y;
        }
        accx += (ax0 + ax1) + (ax2 + ax3);
        accy += (ay0 + ay1) + (ay2 + ay3);
    }
    float inv = 1.f / denom;
    int j0 = h * 128 + 2 * lane;
    float o0 = fmaxf(accx * inv + bias[j0], 0.f);
    float o1 = fmaxf(accy * inv + bias[j0 + 1], 0.f);
    if (POOL) {
        int b = batch[node];
        atomicAdd(&gsum[b * 128 + j0], o0);
        atomicAdd(&gsum[b * 128 + j0 + 1], o1);
        if (lane == 0) atomicAdd(&gcnt[b], 1.f);
    } else {
        float2* op = (float2*)(out + (size_t)node * (H * 128));
        op[h * 64 + lane] = make_float2(o0, o1);
    }
}

// xl2 = h @ W2 : [N,512]@[512,128], fused with GAT2 attention scores.
// 512 threads, 16 nodes/block (625 blocks). Thread t: col j=t&127, rg=t>>7 -> 4 nodes.
__global__ void __launch_bounds__(512)
xw2_attn(const float* __restrict__ h, const float* __restrict__ W2,
         const float* __restrict__ a_src2, const float* __restrict__ a_dst2,
         float* __restrict__ xl2, float* __restrict__ es2, float* __restrict__ ed2, int n) {
    __shared__ float hs[16][512];
    __shared__ float red[8][4][2];
    int t = threadIdx.x;
    int n0 = blockIdx.x * 16;
    const float4* hsrc = (const float4*)(h + (size_t)n0 * 512);
    float4* hdst = (float4*)&hs[0][0];
#pragma unroll
    for (int i = 0; i < 4; ++i) hdst[t + 512 * i] = hsrc[t + 512 * i];
    __syncthreads();
    int j = t & 127, rg = t >> 7;
    float acc[4] = {0.f, 0.f, 0.f, 0.f};
    for (int k = 0; k < 512; k += 4) {
        float w0 = W2[(k + 0) * 128 + j];
        float w1 = W2[(k + 1) * 128 + j];
        float w2 = W2[(k + 2) * 128 + j];
        float w3 = W2[(k + 3) * 128 + j];
#pragma unroll
        for (int r = 0; r < 4; ++r) {
            float4 hv = *(const float4*)&hs[rg * 4 + r][k];
            acc[r] += hv.x * w0 + hv.y * w1 + hv.z * w2 + hv.w * w3;
        }
    }
#pragma unroll
    for (int r = 0; r < 4; ++r)
        xl2[(size_t)(n0 + rg * 4 + r) * 128 + j] = acc[r];
    // fused attention scores: es2[n] = sum_j xl2[n,j]*a_src2[j] (reduce over 2 waves per rg)
    float as = a_src2[j], ad = a_dst2[j];
    float ps[4], pd[4];
#pragma unroll
    for (int r = 0; r < 4; ++r) { ps[r] = acc[r] * as; pd[r] = acc[r] * ad; }
#pragma unroll
    for (int off = 32; off; off >>= 1) {
#pragma unroll
        for (int r = 0; r < 4; ++r) {
            ps[r] += __shfl_xor(ps[r], off);
            pd[r] += __shfl_xor(pd[r], off);
        }
    }
    int wave = t >> 6;
    if ((t & 63) == 0) {
#pragma unroll
        for (int r = 0; r < 4; ++r) { red[wave][r][0] = ps[r]; red[wave][r][1] = pd[r]; }
    }
    __syncthreads();
    if (t < 16) {
        int r = t & 3, g = t >> 2;   // node = n0 + g*4 + r, served by waves 2g, 2g+1
        es2[n0 + g * 4 + r] = red[2 * g][r][0] + red[2 * g + 1][r][0];
        ed2[n0 + g * 4 + r] = red[2 * g][r][1] + red[2 * g + 1][r][1];
    }
}

// MLP head: one block (128 threads) per graph
__global__ void mlp_kernel(const float* __restrict__ gsum, const float* __restrict__ gcnt,
                           const float* __restrict__ mw1, const float* __restrict__ mb1,
                           const float* __restrict__ mw2, const float* __restrict__ mb2,
                           float* __restrict__ out) {
    __shared__ float gm[128], tbuf[128];
    int g = blockIdx.x, j = threadIdx.x;
    float cnt = fmaxf(gcnt[g], 1.f);
    gm[j] = gsum[g * 128 + j] / cnt;
    __syncthreads();
    float s = mb1[j];
    for (int k = 0; k < 128; ++k) s += gm[k] * mw1[k * 128 + j];
    tbuf[j] = fmaxf(s, 0.f);
    __syncthreads();
    if (j < 4) {
        float o = mb2[j];
        for (int k = 0; k < 128; ++k) o += tbuf[k] * mw2[k * 4 + j];
        out[g * 4 + j] = o;
    }
}

extern "C" void kernel_launch(void* const* d_in, const int* in_sizes, int n_in,
                              void* d_out, int out_size, void* d_ws, size_t ws_size,
                              hipStream_t stream) {
    const float* x       = (const float*)d_in[0];
    const int*   ei      = (const int*)d_in[1];
    const int*   batch   = (const int*)d_in[2];
    const float* W1      = (const float*)d_in[3];
    const float* a_src1  = (const float*)d_in[4];
    const float* a_dst1  = (const float*)d_in[5];
    const float* b1      = (const float*)d_in[6];
    const float* W2      = (const float*)d_in[7];
    const float* a_src2  = (const float*)d_in[8];
    const float* a_dst2  = (const float*)d_in[9];
    const float* b2      = (const float*)d_in[10];
    const float* mw1     = (const float*)d_in[11];
    const float* mb1     = (const float*)d_in[12];
    const float* mw2     = (const float*)d_in[13];
    const float* mb2     = (const float*)d_in[14];
    float* out = (float*)d_out;

    const int N = in_sizes[0] / 6;      // 10000
    const int E = in_sizes[1] / 2;      // 160000
    const int ET = E + N;               // with self-loops
    const int G = 64;

    char* ws = (char*)d_ws;
    size_t off = 0;
    auto alloc = [&](size_t bytes) {
        void* p = ws + off;
        off += (bytes + 15) & ~(size_t)15;
        return p;
    };
    float* xl1     = (float*)alloc((size_t)N * 512 * 4);
    float* hbuf    = (float*)alloc((size_t)N * 512 * 4);
    float* xl2     = (float*)alloc((size_t)N * 128 * 4);
    float* es1     = (float*)alloc((size_t)N * 4 * 4);
    float* ed1     = (float*)alloc((size_t)N * 4 * 4);
    float* es2     = (float*)alloc((size_t)N * 4);
    float* ed2     = (float*)alloc((size_t)N * 4);
    int*   offsets = (int*)alloc((size_t)(N + 1) * 4);
    int*   zbase   = (int*)alloc((size_t)N * 4 + (size_t)N * 4 + (size_t)G * 128 * 4 + (size_t)G * 4);
    int*   deg     = zbase;
    int*   cursor  = zbase + N;
    float* gsum    = (float*)(zbase + 2 * N);
    float* gcnt    = gsum + G * 128;
    int*   csr_src = (int*)alloc((size_t)ET * 4);
    (void)ws_size; (void)n_in; (void)out_size;

    const int zn = 2 * N + G * 128 + G;

    zero_kernel<<<(zn + 255) / 256, 256, 0, stream>>>(zbase, zn);
    deg_kernel<<<(ET + 255) / 256, 256, 0, stream>>>(ei, E, N, deg);
    scan_kernel<<<1, 1024, 0, stream>>>(deg, offsets, N);
    fill_kernel<<<(ET + 255) / 256, 256, 0, stream>>>(ei, E, N, offsets, cursor, csr_src);

    xw1_attn<<<N, 256, 0, stream>>>(x, W1, a_src1, a_dst1, xl1, es1, ed1, N);
    gat_agg<4, false><<<N, 256, 0, stream>>>(xl1, es1, ed1, offsets, csr_src, b1,
                                             hbuf, nullptr, nullptr, nullptr, N);
    xw2_attn<<<N / 16, 512, 0, stream>>>(hbuf, W2, a_src2, a_dst2, xl2, es2, ed2, N);
    gat_agg<1, true><<<N / 4, 256, 0, stream>>>(xl2, es2, ed2, offsets, csr_src, b2,
                                                nullptr, batch, gsum, gcnt, N);
    mlp_kernel<<<G, 128, 0, stream>>>(gsum, gcnt, mw1, mb1, mw2, mb2, out);
}

// Round 5
// 275.928 us; speedup vs baseline: 1.2720x; 1.0497x over previous
//
#include <hip/hip_runtime.h>
#include <hip/hip_fp16.h>

#define NEG_SLOPE 0.2f

// -------- edge helpers: edge_index is [2,E] int32 row-major; self-loops appended --------
__device__ __forceinline__ void edge_sd(const int* ei, int E, int e, int& s, int& d) {
    if (e < E) { s = ei[e]; d = ei[E + e]; }
    else       { int v = e - E; s = v; d = v; }
}

__global__ void zero_kernel(int* p, int n) {
    int i = blockIdx.x * blockDim.x + threadIdx.x;
    if (i < n) p[i] = 0;
}

__global__ void deg_kernel(const int* ei, int E, int N, int* deg) {
    int e = blockIdx.x * blockDim.x + threadIdx.x;
    if (e >= E + N) return;
    int s, d; edge_sd(ei, E, e, s, d);
    atomicAdd(&deg[d], 1);
}

// single-block exclusive scan of deg[0..n) -> offsets[0..n], offsets[n] = total
__global__ void scan_kernel(const int* deg, int* offsets, int n) {
    __shared__ int part[1024];
    int t = threadIdx.x;
    int chunk = (n + 1023) / 1024;
    int beg = t * chunk;
    int s = 0;
    for (int i = 0; i < chunk; ++i) {
        int idx = beg + i;
        if (idx < n) s += deg[idx];
    }
    part[t] = s;
    __syncthreads();
    for (int off = 1; off < 1024; off <<= 1) {
        int v = (t >= off) ? part[t - off] : 0;
        __syncthreads();
        part[t] += v;
        __syncthreads();
    }
    if (t == 1023) offsets[n] = part[1023];
    int run = (t == 0) ? 0 : part[t - 1];
    for (int i = 0; i < chunk; ++i) {
        int idx = beg + i;
        if (idx < n) { offsets[idx] = run; run += deg[idx]; }
    }
}

__global__ void fill_kernel(const int* ei, int E, int N, const int* offsets,
                            int* cursor, int* csr_src) {
    int e = blockIdx.x * blockDim.x + threadIdx.x;
    if (e >= E + N) return;
    int s, d; edge_sd(ei, E, e, s, d);
    int pos = offsets[d] + atomicAdd(&cursor[d], 1);
    csr_src[pos] = s;
}

// Fused: xl1 = x@W1 (per node, 512 outputs, stored fp16 for the gather path)
// + es1/ed1 attention scores (computed in f32). Block = 256 thr; wave = head.
__global__ void xw1_attn(const float* __restrict__ x, const float* __restrict__ W1,
                         const float* __restrict__ a_src, const float* __restrict__ a_dst,
                         __half2* __restrict__ xlh, float* __restrict__ es, float* __restrict__ ed,
                         int n) {
    int node = blockIdx.x;
    int t = threadIdx.x;
    __shared__ float xs[6];
    if (t < 6) xs[t] = x[node * 6 + t];
    __syncthreads();
    int j0 = 2 * t, j1 = 2 * t + 1;
    float v0 = 0.f, v1 = 0.f;
#pragma unroll
    for (int k = 0; k < 6; ++k) {
        v0 += xs[k] * W1[k * 512 + j0];
        v1 += xs[k] * W1[k * 512 + j1];
    }
    xlh[(size_t)node * 256 + t] = __floats2half2_rn(v0, v1);
    float ps = v0 * a_src[j0] + v1 * a_src[j1];
    float pd = v0 * a_dst[j0] + v1 * a_dst[j1];
#pragma unroll
    for (int off = 32; off; off >>= 1) {
        ps += __shfl_xor(ps, off);
        pd += __shfl_xor(pd, off);
    }
    int h = t >> 6, lane = t & 63;
    if (lane == 0) { es[node * 4 + h] = ps; ed[node * 4 + h] = pd; }
}

// Aggregation. H=4: one node per block (256 thr), wave = head.
//              H=1: four nodes per block (256 thr), wave = node.
// Phase a (lane-parallel): <=64 edge weights at once, wave-reduce max/sum, exp.
// Phase b: fp16 feature gather, 1 dword load per edge, 8 edges in flight.
template <int H, bool POOL>
__global__ void gat_agg(const __half* __restrict__ xlh, const float* __restrict__ es,
                        const float* __restrict__ ed, const int* __restrict__ offsets,
                        const int* __restrict__ csr_src, const float* __restrict__ bias,
                        float* __restrict__ out, const int* __restrict__ batch,
                        float* __restrict__ gsum, float* __restrict__ gcnt, int n) {
    int wave = threadIdx.x >> 6;
    int lane = threadIdx.x & 63;
    int node, h;
    if (H == 4) { node = blockIdx.x; h = wave; }
    else        { node = blockIdx.x * 4 + wave; h = 0; }
    int beg = offsets[node], end = offsets[node + 1];
    float edv = ed[node * H + h];
    float m = -1e30f, denom = 0.f;
    float accx = 0.f, accy = 0.f;
    for (int chunk = beg; chunk < end; chunk += 64) {
        int i = chunk + lane;
        bool valid = i < end;
        int s = valid ? csr_src[i] : 0;
        float w = -1e30f;
        if (valid) {
            w = es[s * H + h] + edv;
            w = (w > 0.f) ? w : NEG_SLOPE * w;
        }
        float cm = w;
#pragma unroll
        for (int off = 32; off; off >>= 1) cm = fmaxf(cm, __shfl_xor(cm, off));
        float newm = fmaxf(m, cm);
        float scale = __expf(m - newm);   // first chunk: exp(-huge)=0, acc/denom are 0
        accx *= scale; accy *= scale; denom *= scale;
        float ex = valid ? __expf(w - newm) : 0.f;
        float sum = ex;
#pragma unroll
        for (int off = 32; off; off >>= 1) sum += __shfl_xor(sum, off);
        denom += sum;
        m = newm;
        int cnt = end - chunk; if (cnt > 64) cnt = 64;
        float ax0 = 0.f, ay0 = 0.f, ax1 = 0.f, ay1 = 0.f;
        float ax2 = 0.f, ay2 = 0.f, ax3 = 0.f, ay3 = 0.f;
        int tt = 0;
        for (; tt + 8 <= cnt; tt += 8) {
            float w0 = __shfl(ex, tt    ), w1 = __shfl(ex, tt + 1);
            float w2 = __shfl(ex, tt + 2), w3 = __shfl(ex, tt + 3);
            float w4 = __shfl(ex, tt + 4), w5 = __shfl(ex, tt + 5);
            float w6 = __shfl(ex, tt + 6), w7 = __shfl(ex, tt + 7);
            int s0 = __shfl(s, tt    ), s1 = __shfl(s, tt + 1);
            int s2 = __shfl(s, tt + 2), s3 = __shfl(s, tt + 3);
            int s4 = __shfl(s, tt + 4), s5 = __shfl(s, tt + 5);
            int s6 = __shfl(s, tt + 6), s7 = __shfl(s, tt + 7);
            __half2 v0 = ((const __half2*)(xlh + ((size_t)s0 * H + h) * 128))[lane];
            __half2 v1 = ((const __half2*)(xlh + ((size_t)s1 * H + h) * 128))[lane];
            __half2 v2 = ((const __half2*)(xlh + ((size_t)s2 * H + h) * 128))[lane];
            __half2 v3 = ((const __half2*)(xlh + ((size_t)s3 * H + h) * 128))[lane];
            __half2 v4 = ((const __half2*)(xlh + ((size_t)s4 * H + h) * 128))[lane];
            __half2 v5 = ((const __half2*)(xlh + ((size_t)s5 * H + h) * 128))[lane];
            __half2 v6 = ((const __half2*)(xlh + ((size_t)s6 * H + h) * 128))[lane];
            __half2 v7 = ((const __half2*)(xlh + ((size_t)s7 * H + h) * 128))[lane];
            float2 f0 = __half22float2(v0), f1 = __half22float2(v1);
            float2 f2 = __half22float2(v2), f3 = __half22float2(v3);
            float2 f4 = __half22float2(v4), f5 = __half22float2(v5);
            float2 f6 = __half22float2(v6), f7 = __half22float2(v7);
            ax0 += w0 * f0.x; ay0 += w0 * f0.y;
            ax1 += w1 * f1.x; ay1 += w1 * f1.y;
            ax2 += w2 * f2.x; ay2 += w2 * f2.y;
            ax3 += w3 * f3.x; ay3 += w3 * f3.y;
            ax0 += w4 * f4.x; ay0 += w4 * f4.y;
            ax1 += w5 * f5.x; ay1 += w5 * f5.y;
            ax2 += w6 * f6.x; ay2 += w6 * f6.y;
            ax3 += w7 * f7.x; ay3 += w7 * f7.y;
        }
        for (; tt < cnt; ++tt) {
            float wt = __shfl(ex, tt);
            int st = __shfl(s, tt);
            __half2 v = ((const __half2*)(xlh + ((size_t)st * H + h) * 128))[lane];
            float2 f = __half22float2(v);
            ax0 += wt * f.x; ay0 += wt * f.y;
        }
        accx += (ax0 + ax1) + (ax2 + ax3);
        accy += (ay0 + ay1) + (ay2 + ay3);
    }
    float inv = 1.f / denom;
    int j0 = h * 128 + 2 * lane;
    float o0 = fmaxf(accx * inv + bias[j0], 0.f);
    float o1 = fmaxf(accy * inv + bias[j0 + 1], 0.f);
    if (POOL) {
        int b = batch[node];
        atomicAdd(&gsum[b * 128 + j0], o0);
        atomicAdd(&gsum[b * 128 + j0 + 1], o1);
        if (lane == 0) atomicAdd(&gcnt[b], 1.f);
    } else {
        float2* op = (float2*)(out + (size_t)node * (H * 128));
        op[h * 64 + lane] = make_float2(o0, o1);
    }
}

// xl2 = h @ W2 : [N,512]@[512,128] (stored fp16), fused with GAT2 attention scores.
// 512 threads, 16 nodes/block (625 blocks). Thread t: col j=t&127, rg=t>>7 -> 4 nodes.
__global__ void __launch_bounds__(512)
xw2_attn(const float* __restrict__ h, const float* __restrict__ W2,
         const float* __restrict__ a_src2, const float* __restrict__ a_dst2,
         __half* __restrict__ xl2h, float* __restrict__ es2, float* __restrict__ ed2, int n) {
    __shared__ float hs[16][512];
    __shared__ float red[8][4][2];
    int t = threadIdx.x;
    int n0 = blockIdx.x * 16;
    const float4* hsrc = (const float4*)(h + (size_t)n0 * 512);
    float4* hdst = (float4*)&hs[0][0];
#pragma unroll
    for (int i = 0; i < 4; ++i) hdst[t + 512 * i] = hsrc[t + 512 * i];
    __syncthreads();
    int j = t & 127, rg = t >> 7;
    float acc[4] = {0.f, 0.f, 0.f, 0.f};
    for (int k = 0; k < 512; k += 4) {
        float w0 = W2[(k + 0) * 128 + j];
        float w1 = W2[(k + 1) * 128 + j];
        float w2 = W2[(k + 2) * 128 + j];
        float w3 = W2[(k + 3) * 128 + j];
#pragma unroll
        for (int r = 0; r < 4; ++r) {
            float4 hv = *(const float4*)&hs[rg * 4 + r][k];
            acc[r] += hv.x * w0 + hv.y * w1 + hv.z * w2 + hv.w * w3;
        }
    }
#pragma unroll
    for (int r = 0; r < 4; ++r)
        xl2h[(size_t)(n0 + rg * 4 + r) * 128 + j] = __float2half_rn(acc[r]);
    // fused attention scores: es2[n] = sum_j xl2[n,j]*a_src2[j] (reduce over 2 waves per rg)
    float as = a_src2[j], ad = a_dst2[j];
    float ps[4], pd[4];
#pragma unroll
    for (int r = 0; r < 4; ++r) { ps[r] = acc[r] * as; pd[r] = acc[r] * ad; }
#pragma unroll
    for (int off = 32; off; off >>= 1) {
#pragma unroll
        for (int r = 0; r < 4; ++r) {
            ps[r] += __shfl_xor(ps[r], off);
            pd[r] += __shfl_xor(pd[r], off);
        }
    }
    int wave = t >> 6;
    if ((t & 63) == 0) {
#pragma unroll
        for (int r = 0; r < 4; ++r) { red[wave][r][0] = ps[r]; red[wave][r][1] = pd[r]; }
    }
    __syncthreads();
    if (t < 16) {
        int r = t & 3, g = t >> 2;   // node = n0 + g*4 + r, served by waves 2g, 2g+1
        es2[n0 + g * 4 + r] = red[2 * g][r][0] + red[2 * g + 1][r][0];
        ed2[n0 + g * 4 + r] = red[2 * g][r][1] + red[2 * g + 1][r][1];
    }
}

// MLP head: one block (128 threads) per graph
__global__ void mlp_kernel(const float* __restrict__ gsum, const float* __restrict__ gcnt,
                           const float* __restrict__ mw1, const float* __restrict__ mb1,
                           const float* __restrict__ mw2, const float* __restrict__ mb2,
                           float* __restrict__ out) {
    __shared__ float gm[128], tbuf[128];
    int g = blockIdx.x, j = threadIdx.x;
    float cnt = fmaxf(gcnt[g], 1.f);
    gm[j] = gsum[g * 128 + j] / cnt;
    __syncthreads();
    float s = mb1[j];
    for (int k = 0; k < 128; ++k) s += gm[k] * mw1[k * 128 + j];
    tbuf[j] = fmaxf(s, 0.f);
    __syncthreads();
    if (j < 4) {
        float o = mb2[j];
        for (int k = 0; k < 128; ++k) o += tbuf[k] * mw2[k * 4 + j];
        out[g * 4 + j] = o;
    }
}

extern "C" void kernel_launch(void* const* d_in, const int* in_sizes, int n_in,
                              void* d_out, int out_size, void* d_ws, size_t ws_size,
                              hipStream_t stream) {
    const float* x       = (const float*)d_in[0];
    const int*   ei      = (const int*)d_in[1];
    const int*   batch   = (const int*)d_in[2];
    const float* W1      = (const float*)d_in[3];
    const float* a_src1  = (const float*)d_in[4];
    const float* a_dst1  = (const float*)d_in[5];
    const float* b1      = (const float*)d_in[6];
    const float* W2      = (const float*)d_in[7];
    const float* a_src2  = (const float*)d_in[8];
    const float* a_dst2  = (const float*)d_in[9];
    const float* b2      = (const float*)d_in[10];
    const float* mw1     = (const float*)d_in[11];
    const float* mb1     = (const float*)d_in[12];
    const float* mw2     = (const float*)d_in[13];
    const float* mb2     = (const float*)d_in[14];
    float* out = (float*)d_out;

    const int N = in_sizes[0] / 6;      // 10000
    const int E = in_sizes[1] / 2;      // 160000
    const int ET = E + N;               // with self-loops
    const int G = 64;

    char* ws = (char*)d_ws;
    size_t off = 0;
    auto alloc = [&](size_t bytes) {
        void* p = ws + off;
        off += (bytes + 15) & ~(size_t)15;
        return p;
    };
    __half* xl1h   = (__half*)alloc((size_t)N * 512 * 2);
    float*  hbuf   = (float*)alloc((size_t)N * 512 * 4);
    __half* xl2h   = (__half*)alloc((size_t)N * 128 * 2);
    float*  es1    = (float*)alloc((size_t)N * 4 * 4);
    float*  ed1    = (float*)alloc((size_t)N * 4 * 4);
    float*  es2    = (float*)alloc((size_t)N * 4);
    float*  ed2    = (float*)alloc((size_t)N * 4);
    int*    offsets= (int*)alloc((size_t)(N + 1) * 4);
    int*    zbase  = (int*)alloc((size_t)N * 4 + (size_t)N * 4 + (size_t)G * 128 * 4 + (size_t)G * 4);
    int*    deg    = zbase;
    int*    cursor = zbase + N;
    float*  gsum   = (float*)(zbase + 2 * N);
    float*  gcnt   = gsum + G * 128;
    int*    csr_src= (int*)alloc((size_t)ET * 4);
    (void)ws_size; (void)n_in; (void)out_size;

    const int zn = 2 * N + G * 128 + G;

    zero_kernel<<<(zn + 255) / 256, 256, 0, stream>>>(zbase, zn);
    deg_kernel<<<(ET + 255) / 256, 256, 0, stream>>>(ei, E, N, deg);
    scan_kernel<<<1, 1024, 0, stream>>>(deg, offsets, N);
    fill_kernel<<<(ET + 255) / 256, 256, 0, stream>>>(ei, E, N, offsets, cursor, csr_src);

    xw1_attn<<<N, 256, 0, stream>>>(x, W1, a_src1, a_dst1, (__half2*)xl1h, es1, ed1, N);
    gat_agg<4, false><<<N, 256, 0, stream>>>(xl1h, es1, ed1, offsets, csr_src, b1,
                                             hbuf, nullptr, nullptr, nullptr, N);
    xw2_attn<<<N / 16, 512, 0, stream>>>(hbuf, W2, a_src2, a_dst2, xl2h, es2, ed2, N);
    gat_agg<1, true><<<N / 4, 256, 0, stream>>>(xl2h, es2, ed2, offsets, csr_src, b2,
                                                nullptr, batch, gsum, gcnt, N);
    mlp_kernel<<<G, 128, 0, stream>>>(gsum, gcnt, mw1, mb1, mw2, mb2, out);
}